// Round 12
// baseline (165.341 us; speedup 1.0000x reference)
//
#include <hip/hip_runtime.h>

// AdditiveAttention: b=4, n_q=64, s=1024, Q_DIM=K_DIM=HID=VDIM=512, f32 in/out.
// R12: R10 pipeline (R11's scores+av fusion regressed: 2 blocks/CU + serial AV
// tail). 4 nodes: convert, proj(MFMA->Eq/Ek=exp2), scores(2-way h-split,
// d=fma(Eq,Ek,1), paired rcp), av_reduce (av partials + spin grid-barrier —
// 256 blocks <= 256 CUs so co-residency is guaranteed — then in-kernel reduce).

static constexpr int SLEN = 1024;
static constexpr int DIM  = 512;
static constexpr float TANH_SCALE = 2.885390081777927f;  // 2*log2(e)

typedef __attribute__((ext_vector_type(8))) short bf16x8;
typedef __attribute__((ext_vector_type(4))) float f32x4;

__device__ __forceinline__ float fast_exp2(float x) { return __builtin_amdgcn_exp2f(x); }
__device__ __forceinline__ float fast_rcp(float x)  { return __builtin_amdgcn_rcpf(x); }

__device__ __forceinline__ unsigned int f2bf(float f) {
    unsigned int u = __float_as_uint(f);
    u += 0x7FFF + ((u >> 16) & 1);   // RNE
    return u >> 16;
}

__device__ __forceinline__ void async_copy16(const void* g, void* l) {
    __builtin_amdgcn_global_load_lds(
        (const __attribute__((address_space(1))) unsigned int*)g,
        (__attribute__((address_space(3))) unsigned int*)l, 16, 0, 0);
}

// f32 -> bf16 pre-convert: queries (131072), keys (2097152), W1 (524288) elems.
__global__ __launch_bounds__(256) void convert_bf16(
    const float* __restrict__ q, const float* __restrict__ k,
    const float* __restrict__ w, unsigned short* __restrict__ qb,
    unsigned short* __restrict__ kb, unsigned short* __restrict__ wb)
{
    int id = blockIdx.x * 256 + threadIdx.x;
    const float* src; unsigned short* dst; int off;
    if (id < 32768)        { src = q; dst = qb; off = id; }
    else if (id < 557056)  { src = k; dst = kb; off = id - 32768; }
    else                   { src = w; dst = wb; off = id - 557056; }
    float4 v = ((const float4*)src)[off];
    ushort4 o;
    o.x = (unsigned short)f2bf(v.x); o.y = (unsigned short)f2bf(v.y);
    o.z = (unsigned short)f2bf(v.z); o.w = (unsigned short)f2bf(v.w);
    ((ushort4*)dst)[off] = o;
}

// Fused q_proj/k_proj GEMM, bf16 MFMA, global_load_lds staging.
// E[m][n] = exp2( (sum_k A[m][k]*W1[n][col_off+k] + bias[n]) * TANH_SCALE )
// blocks 0..511: k_proj -> Ek; 512..543: q_proj -> Eq. Tile 64x64, BK=64.
__global__ __launch_bounds__(256) void proj_mfma(
    const unsigned short* __restrict__ qb, const unsigned short* __restrict__ kb,
    const unsigned short* __restrict__ wb, const float* __restrict__ b1,
    float* __restrict__ qp, float* __restrict__ kp)
{
    __shared__ __align__(16) unsigned short As[64][64];
    __shared__ __align__(16) unsigned short Ws[64][64];

    const int bx = blockIdx.x;
    const unsigned short* A; float* C; const float* bias; int mb, nb, col_off;
    if (bx < 512) {
        A = kb; C = kp; bias = b1; col_off = 512;
        mb = (bx >> 3) * 64; nb = (bx & 7) * 64;
    } else {
        int b2 = bx - 512;
        A = qb; C = qp; bias = nullptr; col_off = 0;
        mb = (b2 >> 3) * 64; nb = (b2 & 7) * 64;
    }

    const int t = threadIdx.x;
    const int l = t & 63;
    const int wv = t >> 6;
    const int wm = (wv & 1) * 32;
    const int wn = (wv >> 1) * 32;
    const int lane16 = l & 15;
    const int quad   = l >> 4;
    const int r8   = l >> 3;
    const int schk = (l & 7) ^ r8;

    f32x4 acc[2][2] = {{{0.f,0.f,0.f,0.f},{0.f,0.f,0.f,0.f}},
                       {{0.f,0.f,0.f,0.f},{0.f,0.f,0.f,0.f}}};

    for (int kc = 0; kc < DIM; kc += 64) {
#pragma unroll
        for (int i = 0; i < 2; ++i) {
            int rbase = wv * 16 + i * 8;
            async_copy16(A + (size_t)(mb + rbase + r8) * DIM + kc + schk * 8, &As[rbase][0]);
            async_copy16(wb + (size_t)(nb + rbase + r8) * 1024 + col_off + kc + schk * 8, &Ws[rbase][0]);
        }
        __syncthreads();

#pragma unroll
        for (int ks = 0; ks < 2; ++ks) {
            int cc = ks * 4 + quad;
            int sw = (cc ^ (lane16 & 7)) << 3;
            bf16x8 a0  = *(const bf16x8*)&As[wm + lane16][sw];
            bf16x8 a1  = *(const bf16x8*)&As[wm + 16 + lane16][sw];
            bf16x8 b0  = *(const bf16x8*)&Ws[wn + lane16][sw];
            bf16x8 b1v = *(const bf16x8*)&Ws[wn + 16 + lane16][sw];
            acc[0][0] = __builtin_amdgcn_mfma_f32_16x16x32_bf16(a0, b0,  acc[0][0], 0, 0, 0);
            acc[0][1] = __builtin_amdgcn_mfma_f32_16x16x32_bf16(a0, b1v, acc[0][1], 0, 0, 0);
            acc[1][0] = __builtin_amdgcn_mfma_f32_16x16x32_bf16(a1, b0,  acc[1][0], 0, 0, 0);
            acc[1][1] = __builtin_amdgcn_mfma_f32_16x16x32_bf16(a1, b1v, acc[1][1], 0, 0, 0);
        }
        __syncthreads();
    }

#pragma unroll
    for (int mi = 0; mi < 2; ++mi) {
#pragma unroll
        for (int ni = 0; ni < 2; ++ni) {
            int col = nb + wn + 16 * ni + lane16;
            float bv = bias ? bias[col] : 0.0f;
#pragma unroll
            for (int r = 0; r < 4; ++r) {
                int row = mb + wm + 16 * mi + quad * 4 + r;
                C[(size_t)row * DIM + col] = fast_exp2((acc[mi][ni][r] + bv) * TANH_SCALE);
            }
        }
    }
}

// th[half][b,q,s] = -TANH_SCALE * sum_{h in half} w2[h]/(1 + Eq[q][h]*Ek[s][h])
// d = fma(Eq,Ek,1): no exp2 in inner loop. Paired rcp. Tile 16q x 32s,
// 4 acc chains. Grid (32, 8, 4) = 1024 blocks (16 waves/CU).
// Block (0,0,0) also zeroes the av grid-barrier counter (ordered by graph edge).
__global__ __launch_bounds__(256) void scores_kernel(
    const float* __restrict__ qp, const float* __restrict__ kp,
    const float* __restrict__ w2, float* __restrict__ th,
    unsigned int* __restrict__ counter)
{
    __shared__ __align__(16) float qs[16][68];
    __shared__ __align__(16) float ks[32][68];
    __shared__ __align__(16) float ws2[256];
    const int t     = threadIdx.x;
    if (t == 0 && blockIdx.x == 0 && blockIdx.y == 0 && blockIdx.z == 0)
        *counter = 0;
    const int sb    = blockIdx.x * 32;
    const int qt    = blockIdx.y & 3;
    const int half  = blockIdx.y >> 2;
    const int kbase = half * 256;
    const int qrow0 = blockIdx.z * 64 + qt * 16;
    const int krow0 = blockIdx.z * 1024 + sb;
    float* thh = th + (size_t)half * 256 * SLEN;

    if (t < 64) *(float4*)&ws2[t << 2] = *(const float4*)(w2 + kbase + (t << 2));

    const int tq = t >> 4;
    const int ts = t & 15;
    float a00 = 0.f, a01 = 0.f, a10 = 0.f, a11 = 0.f;

    for (int kc = 0; kc < 256; kc += 64) {
        {
            int r = t >> 4, g = (t & 15) << 2;
            *(float4*)&qs[r][g] = *(const float4*)(qp + (size_t)(qrow0 + r) * DIM + kbase + kc + g);
        }
#pragma unroll
        for (int rr = 0; rr < 2; ++rr) {
            int idx = t + rr * 256;
            int r = idx >> 4, g = (idx & 15) << 2;
            *(float4*)&ks[r][g] = *(const float4*)(kp + (size_t)(krow0 + r) * DIM + kbase + kc + g);
        }
        __syncthreads();
#pragma unroll
        for (int k4 = 0; k4 < 16; ++k4) {
            float4 qv = *(const float4*)&qs[tq][k4 << 2];
            float4 k0 = *(const float4*)&ks[ts][k4 << 2];
            float4 k1 = *(const float4*)&ks[ts + 16][k4 << 2];
            float4 wv = *(const float4*)&ws2[kc + (k4 << 2)];
            {
                float d0 = fmaf(qv.x, k0.x, 1.0f);
                float d1 = fmaf(qv.y, k0.y, 1.0f);
                a00 = fmaf(fmaf(wv.x, d1, wv.y * d0), fast_rcp(d0 * d1), a00);
                float d2 = fmaf(qv.z, k0.z, 1.0f);
                float d3 = fmaf(qv.w, k0.w, 1.0f);
                a01 = fmaf(fmaf(wv.z, d3, wv.w * d2), fast_rcp(d2 * d3), a01);
            }
            {
                float d0 = fmaf(qv.x, k1.x, 1.0f);
                float d1 = fmaf(qv.y, k1.y, 1.0f);
                a10 = fmaf(fmaf(wv.x, d1, wv.y * d0), fast_rcp(d0 * d1), a10);
                float d2 = fmaf(qv.z, k1.z, 1.0f);
                float d3 = fmaf(qv.w, k1.w, 1.0f);
                a11 = fmaf(fmaf(wv.z, d3, wv.w * d2), fast_rcp(d2 * d3), a11);
            }
        }
        __syncthreads();
    }
    thh[(size_t)(qrow0 + tq) * SLEN + sb + ts]      = -TANH_SCALE * (a00 + a01);
    thh[(size_t)(qrow0 + tq) * SLEN + sb + ts + 16] = -TANH_SCALE * (a10 + a11);
}

// Phase A: pt[kt][b*64+q][v] = sum over 128-s chunk of e*values, e=exp2(th0+th1)
// inline; vt==0 blocks emit per-(kt,row) e-sums via 8-lane shuffle.
// Phase B (after spin grid-barrier; 256 blocks <= 256 CUs => co-resident):
// out = (sum_kt pt) / (sum_kt sums). Grid (8 vt, 8 kt, 4 b) = 256 blocks.
__global__ __launch_bounds__(256) void av_reduce(
    const float* __restrict__ th, const float* __restrict__ values,
    float* __restrict__ pt, float* __restrict__ sums_p,
    unsigned int* __restrict__ counter, float* __restrict__ out)
{
    __shared__ __align__(16) float As[32][68];
    __shared__ __align__(16) float Bs[32][68];
    const int t  = threadIdx.x;
    const int nb = blockIdx.x * 64;
    const int kt = blockIdx.y;
    const int kb = kt * 128;
    const int b  = blockIdx.z;
    const int tx = t & 15, ty = t >> 4;
    float acc[4][4] = {};
    float rsum[2] = {0.f, 0.f};
    for (int kc = 0; kc < 128; kc += 32) {
        const int k0 = kb + kc;
#pragma unroll
        for (int r = 0; r < 2; ++r) {
            int idx = t + r * 256;
            int m   = idx >> 3;
            int k4  = (idx & 7) << 2;
            size_t base = (size_t)(b * 64 + m) * SLEN + k0 + k4;
            float4 t0 = *(const float4*)(th + base);
            float4 t1 = *(const float4*)(th + 262144 + base);
            float4 e;
            e.x = fast_exp2(t0.x + t1.x);
            e.y = fast_exp2(t0.y + t1.y);
            e.z = fast_exp2(t0.z + t1.z);
            e.w = fast_exp2(t0.w + t1.w);
            As[k4 + 0][m] = e.x; As[k4 + 1][m] = e.y;
            As[k4 + 2][m] = e.z; As[k4 + 3][m] = e.w;
            rsum[r] += e.x + e.y + e.z + e.w;
            int kk = idx >> 4;
            int g  = (idx & 15) << 2;
            *(float4*)&Bs[kk][g] =
                *(const float4*)(values + (size_t)(b * 1024 + k0 + kk) * DIM + nb + g);
        }
        __syncthreads();
#pragma unroll
        for (int k = 0; k < 32; ++k) {
            float4 a  = *(const float4*)&As[k][ty << 2];
            float4 bv = *(const float4*)&Bs[k][tx << 2];
            float am[4] = {a.x, a.y, a.z, a.w};
            float bn[4] = {bv.x, bv.y, bv.z, bv.w};
#pragma unroll
            for (int i = 0; i < 4; ++i)
#pragma unroll
                for (int j = 0; j < 4; ++j)
                    acc[i][j] = fmaf(am[i], bn[j], acc[i][j]);
        }
        __syncthreads();
    }
#pragma unroll
    for (int i = 0; i < 4; ++i) {
        int row = b * 64 + (ty << 2) + i;
        float4 o;
        o.x = acc[i][0]; o.y = acc[i][1]; o.z = acc[i][2]; o.w = acc[i][3];
        *(float4*)(pt + ((size_t)kt * 256 + row) * DIM + nb + (tx << 2)) = o;
    }
    if (nb == 0) {
#pragma unroll
        for (int r = 0; r < 2; ++r) {
            float v = rsum[r];
            v += __shfl_xor(v, 1, 64);
            v += __shfl_xor(v, 2, 64);
            v += __shfl_xor(v, 4, 64);
            if ((t & 7) == 0) {
                int m = (t >> 3) + r * 32;
                sums_p[kt * 256 + b * 64 + m] = v;
            }
        }
    }

    // ---- spin grid-barrier (all 256 blocks co-resident) ----
    __threadfence();        // release pt/sums_p stores to device scope
    __syncthreads();
    if (t == 0) {
        atomicAdd(counter, 1u);
        while (__hip_atomic_load(counter, __ATOMIC_RELAXED,
                                 __HIP_MEMORY_SCOPE_AGENT) < 256u) {
            __builtin_amdgcn_s_sleep(2);
        }
    }
    __syncthreads();
    __threadfence();        // acquire

    // ---- Phase B: reduce. 256 blocks x 128 float4s = 32768 ----
    const int bid = blockIdx.x + (blockIdx.y << 3) + (blockIdx.z << 6);
    if (t < 128) {
        int idx = bid * 128 + t;
        const float4* p = (const float4*)pt;
        float4 a = p[idx];
#pragma unroll
        for (int k = 1; k < 8; ++k) {
            float4 v = p[k * 32768 + idx];
            a.x += v.x; a.y += v.y; a.z += v.z; a.w += v.w;
        }
        int row = idx >> 7;
        float s = 0.f;
#pragma unroll
        for (int k = 0; k < 8; ++k) s += sums_p[k * 256 + row];
        float r = fast_rcp(s);
        a.x *= r; a.y *= r; a.z *= r; a.w *= r;
        ((float4*)out)[idx] = a;
    }
}

extern "C" void kernel_launch(void* const* d_in, const int* in_sizes, int n_in,
                              void* d_out, int out_size, void* d_ws, size_t ws_size,
                              hipStream_t stream) {
    const float* queries = (const float*)d_in[0];
    const float* keys    = (const float*)d_in[1];
    const float* values  = (const float*)d_in[2];
    const float* W1      = (const float*)d_in[3];
    const float* b1      = (const float*)d_in[4];
    const float* w2      = (const float*)d_in[5];
    float* out = (float*)d_out;

    float* qp     = (float*)d_ws;                   // 131072 f32 (Eq)
    float* kp     = qp + 131072;                    // 2097152 f32 (Ek)
    float* th     = kp + 2097152;                   // 2 x 262144 f32
    float* pt     = th + 2 * 262144;                // 8 x 131072 f32
    float* sums_p = pt + 8 * 131072;                // 2048 f32
    unsigned int* counter = (unsigned int*)(sums_p + 2048);   // 16 f32 slot
    unsigned short* qbf = (unsigned short*)(sums_p + 2048 + 16);
    unsigned short* kbf = qbf + 131072;
    unsigned short* wbf = kbf + 2097152;
    (void)in_sizes; (void)n_in; (void)ws_size; (void)out_size;

    convert_bf16<<<dim3(2688), 256, 0, stream>>>(queries, keys, W1, qbf, kbf, wbf);
    proj_mfma<<<dim3(544), 256, 0, stream>>>(qbf, kbf, wbf, b1, qp, kp);
    scores_kernel<<<dim3(32, 8, 4), 256, 0, stream>>>(qp, kp, w2, th, counter);
    av_reduce<<<dim3(8, 8, 4), 256, 0, stream>>>(th, values, pt, sums_p, counter, out);
}

// Round 13
// 117.720 us; speedup vs baseline: 1.4045x; 1.4045x over previous
//
#include <hip/hip_runtime.h>

// AdditiveAttention: b=4, n_q=64, s=1024, Q_DIM=K_DIM=HID=VDIM=512, f32 in/out.
// R13: R10 pipeline (5 nodes; R12's grid-barrier fusion regressed 47 µs —
// 1 block/CU Phase A + barrier skew; reverted). scores micro-opts: q-tile in
// registers (global broadcast loads, no qs LDS), w2 via wave-uniform s_load
// (no ws2 LDS) -> inner loop 2 ds_read_b128 instead of 4.

static constexpr int SLEN = 1024;
static constexpr int DIM  = 512;
static constexpr float TANH_SCALE = 2.885390081777927f;  // 2*log2(e)

typedef __attribute__((ext_vector_type(8))) short bf16x8;
typedef __attribute__((ext_vector_type(4))) float f32x4;

__device__ __forceinline__ float fast_exp2(float x) { return __builtin_amdgcn_exp2f(x); }
__device__ __forceinline__ float fast_rcp(float x)  { return __builtin_amdgcn_rcpf(x); }

__device__ __forceinline__ unsigned int f2bf(float f) {
    unsigned int u = __float_as_uint(f);
    u += 0x7FFF + ((u >> 16) & 1);   // RNE
    return u >> 16;
}

__device__ __forceinline__ void async_copy16(const void* g, void* l) {
    __builtin_amdgcn_global_load_lds(
        (const __attribute__((address_space(1))) unsigned int*)g,
        (__attribute__((address_space(3))) unsigned int*)l, 16, 0, 0);
}

// f32 -> bf16 pre-convert: queries (131072), keys (2097152), W1 (524288) elems.
__global__ __launch_bounds__(256) void convert_bf16(
    const float* __restrict__ q, const float* __restrict__ k,
    const float* __restrict__ w, unsigned short* __restrict__ qb,
    unsigned short* __restrict__ kb, unsigned short* __restrict__ wb)
{
    int id = blockIdx.x * 256 + threadIdx.x;
    const float* src; unsigned short* dst; int off;
    if (id < 32768)        { src = q; dst = qb; off = id; }
    else if (id < 557056)  { src = k; dst = kb; off = id - 32768; }
    else                   { src = w; dst = wb; off = id - 557056; }
    float4 v = ((const float4*)src)[off];
    ushort4 o;
    o.x = (unsigned short)f2bf(v.x); o.y = (unsigned short)f2bf(v.y);
    o.z = (unsigned short)f2bf(v.z); o.w = (unsigned short)f2bf(v.w);
    ((ushort4*)dst)[off] = o;
}

// Fused q_proj/k_proj GEMM, bf16 MFMA, global_load_lds staging.
// E[m][n] = exp2( (sum_k A[m][k]*W1[n][col_off+k] + bias[n]) * TANH_SCALE )
// blocks 0..511: k_proj -> Ek; 512..543: q_proj -> Eq. Tile 64x64, BK=64.
__global__ __launch_bounds__(256) void proj_mfma(
    const unsigned short* __restrict__ qb, const unsigned short* __restrict__ kb,
    const unsigned short* __restrict__ wb, const float* __restrict__ b1,
    float* __restrict__ qp, float* __restrict__ kp)
{
    __shared__ __align__(16) unsigned short As[64][64];
    __shared__ __align__(16) unsigned short Ws[64][64];

    const int bx = blockIdx.x;
    const unsigned short* A; float* C; const float* bias; int mb, nb, col_off;
    if (bx < 512) {
        A = kb; C = kp; bias = b1; col_off = 512;
        mb = (bx >> 3) * 64; nb = (bx & 7) * 64;
    } else {
        int b2 = bx - 512;
        A = qb; C = qp; bias = nullptr; col_off = 0;
        mb = (b2 >> 3) * 64; nb = (b2 & 7) * 64;
    }

    const int t = threadIdx.x;
    const int l = t & 63;
    const int wv = t >> 6;
    const int wm = (wv & 1) * 32;
    const int wn = (wv >> 1) * 32;
    const int lane16 = l & 15;
    const int quad   = l >> 4;
    const int r8   = l >> 3;
    const int schk = (l & 7) ^ r8;

    f32x4 acc[2][2] = {{{0.f,0.f,0.f,0.f},{0.f,0.f,0.f,0.f}},
                       {{0.f,0.f,0.f,0.f},{0.f,0.f,0.f,0.f}}};

    for (int kc = 0; kc < DIM; kc += 64) {
#pragma unroll
        for (int i = 0; i < 2; ++i) {
            int rbase = wv * 16 + i * 8;
            async_copy16(A + (size_t)(mb + rbase + r8) * DIM + kc + schk * 8, &As[rbase][0]);
            async_copy16(wb + (size_t)(nb + rbase + r8) * 1024 + col_off + kc + schk * 8, &Ws[rbase][0]);
        }
        __syncthreads();

#pragma unroll
        for (int ks = 0; ks < 2; ++ks) {
            int cc = ks * 4 + quad;
            int sw = (cc ^ (lane16 & 7)) << 3;
            bf16x8 a0  = *(const bf16x8*)&As[wm + lane16][sw];
            bf16x8 a1  = *(const bf16x8*)&As[wm + 16 + lane16][sw];
            bf16x8 b0  = *(const bf16x8*)&Ws[wn + lane16][sw];
            bf16x8 b1v = *(const bf16x8*)&Ws[wn + 16 + lane16][sw];
            acc[0][0] = __builtin_amdgcn_mfma_f32_16x16x32_bf16(a0, b0,  acc[0][0], 0, 0, 0);
            acc[0][1] = __builtin_amdgcn_mfma_f32_16x16x32_bf16(a0, b1v, acc[0][1], 0, 0, 0);
            acc[1][0] = __builtin_amdgcn_mfma_f32_16x16x32_bf16(a1, b0,  acc[1][0], 0, 0, 0);
            acc[1][1] = __builtin_amdgcn_mfma_f32_16x16x32_bf16(a1, b1v, acc[1][1], 0, 0, 0);
        }
        __syncthreads();
    }

#pragma unroll
    for (int mi = 0; mi < 2; ++mi) {
#pragma unroll
        for (int ni = 0; ni < 2; ++ni) {
            int col = nb + wn + 16 * ni + lane16;
            float bv = bias ? bias[col] : 0.0f;
#pragma unroll
            for (int r = 0; r < 4; ++r) {
                int row = mb + wm + 16 * mi + quad * 4 + r;
                C[(size_t)row * DIM + col] = fast_exp2((acc[mi][ni][r] + bv) * TANH_SCALE);
            }
        }
    }
}

// th[half][b,q,s] = -TANH_SCALE * sum_{h in half} w2[h]/(1 + Eq[q][h]*Ek[s][h])
// d = fma(Eq,Ek,1); paired rcp. q-row in REGISTERS (16 float4/chunk, global
// broadcast loads), w2 via wave-uniform scalar loads — only k goes through
// LDS (2 ds_read_b128/iter). Tile 16q x 32s. Grid (32, 8, 4) = 1024 blocks,
// 4 blocks/CU (launch_bounds caps VGPR at 128).
__global__ __launch_bounds__(256, 4) void scores_kernel(
    const float* __restrict__ qp, const float* __restrict__ kp,
    const float* __restrict__ w2, float* __restrict__ th)
{
    __shared__ __align__(16) float ks[32][68];
    const int t     = threadIdx.x;
    const int sb    = blockIdx.x * 32;
    const int qt    = blockIdx.y & 3;
    const int half  = blockIdx.y >> 2;
    const int kbase = half * 256;
    const int qrow0 = blockIdx.z * 64 + qt * 16;
    const int krow0 = blockIdx.z * 1024 + sb;
    float* thh = th + (size_t)half * 256 * SLEN;

    const int tq = t >> 4;
    const int ts = t & 15;
    const float* qrow = qp + (size_t)(qrow0 + tq) * DIM + kbase;
    const float* w2b  = w2 + kbase;
    float a00 = 0.f, a01 = 0.f, a10 = 0.f, a11 = 0.f;

    for (int kc = 0; kc < 256; kc += 64) {
        // stage k tile (32 rows x 64 h)
#pragma unroll
        for (int rr = 0; rr < 2; ++rr) {
            int idx = t + rr * 256;
            int r = idx >> 4, g = (idx & 15) << 2;
            *(float4*)&ks[r][g] = *(const float4*)(kp + (size_t)(krow0 + r) * DIM + kbase + kc + g);
        }
        // q chunk into registers (16 lanes share each address -> L1 broadcast)
        float4 qreg[16];
#pragma unroll
        for (int i = 0; i < 16; ++i)
            qreg[i] = *(const float4*)(qrow + kc + (i << 2));
        __syncthreads();
#pragma unroll
        for (int k4 = 0; k4 < 16; ++k4) {
            float4 qv = qreg[k4];
            float4 k0 = *(const float4*)&ks[ts][k4 << 2];
            float4 k1 = *(const float4*)&ks[ts + 16][k4 << 2];
            float4 wv = *(const float4*)(w2b + kc + (k4 << 2));  // uniform -> s_load
            {
                float d0 = fmaf(qv.x, k0.x, 1.0f);
                float d1 = fmaf(qv.y, k0.y, 1.0f);
                a00 = fmaf(fmaf(wv.x, d1, wv.y * d0), fast_rcp(d0 * d1), a00);
                float d2 = fmaf(qv.z, k0.z, 1.0f);
                float d3 = fmaf(qv.w, k0.w, 1.0f);
                a01 = fmaf(fmaf(wv.z, d3, wv.w * d2), fast_rcp(d2 * d3), a01);
            }
            {
                float d0 = fmaf(qv.x, k1.x, 1.0f);
                float d1 = fmaf(qv.y, k1.y, 1.0f);
                a10 = fmaf(fmaf(wv.x, d1, wv.y * d0), fast_rcp(d0 * d1), a10);
                float d2 = fmaf(qv.z, k1.z, 1.0f);
                float d3 = fmaf(qv.w, k1.w, 1.0f);
                a11 = fmaf(fmaf(wv.z, d3, wv.w * d2), fast_rcp(d2 * d3), a11);
            }
        }
        __syncthreads();
    }
    thh[(size_t)(qrow0 + tq) * SLEN + sb + ts]      = -TANH_SCALE * (a00 + a01);
    thh[(size_t)(qrow0 + tq) * SLEN + sb + ts + 16] = -TANH_SCALE * (a10 + a11);
}

// pt[kt][b*64+q][v] = sum over 128-s chunk of e*values, e = exp2(th0+th1)
// inline during staging (unnormalized — safe, |arg|<=35). vt==0 blocks emit
// per-(kt,row) e-sums via 8-lane shuffle. Grid (8 vt, 8 kt, 4 b).
__global__ __launch_bounds__(256) void av_gemm(
    const float* __restrict__ th, const float* __restrict__ values,
    float* __restrict__ pt, float* __restrict__ sums_p)
{
    __shared__ __align__(16) float As[32][68];
    __shared__ __align__(16) float Bs[32][68];
    const int t  = threadIdx.x;
    const int nb = blockIdx.x * 64;
    const int kt = blockIdx.y;
    const int kb = kt * 128;
    const int b  = blockIdx.z;
    const int tx = t & 15, ty = t >> 4;
    float acc[4][4] = {};
    float rsum[2] = {0.f, 0.f};
    for (int kc = 0; kc < 128; kc += 32) {
        const int k0 = kb + kc;
#pragma unroll
        for (int r = 0; r < 2; ++r) {
            int idx = t + r * 256;
            int m   = idx >> 3;
            int k4  = (idx & 7) << 2;
            size_t base = (size_t)(b * 64 + m) * SLEN + k0 + k4;
            float4 t0 = *(const float4*)(th + base);
            float4 t1 = *(const float4*)(th + 262144 + base);
            float4 e;
            e.x = fast_exp2(t0.x + t1.x);
            e.y = fast_exp2(t0.y + t1.y);
            e.z = fast_exp2(t0.z + t1.z);
            e.w = fast_exp2(t0.w + t1.w);
            As[k4 + 0][m] = e.x; As[k4 + 1][m] = e.y;
            As[k4 + 2][m] = e.z; As[k4 + 3][m] = e.w;
            rsum[r] += e.x + e.y + e.z + e.w;
            int kk = idx >> 4;
            int g  = (idx & 15) << 2;
            *(float4*)&Bs[kk][g] =
                *(const float4*)(values + (size_t)(b * 1024 + k0 + kk) * DIM + nb + g);
        }
        __syncthreads();
#pragma unroll
        for (int k = 0; k < 32; ++k) {
            float4 a  = *(const float4*)&As[k][ty << 2];
            float4 bv = *(const float4*)&Bs[k][tx << 2];
            float am[4] = {a.x, a.y, a.z, a.w};
            float bn[4] = {bv.x, bv.y, bv.z, bv.w};
#pragma unroll
            for (int i = 0; i < 4; ++i)
#pragma unroll
                for (int j = 0; j < 4; ++j)
                    acc[i][j] = fmaf(am[i], bn[j], acc[i][j]);
        }
        __syncthreads();
    }
#pragma unroll
    for (int i = 0; i < 4; ++i) {
        int row = b * 64 + (ty << 2) + i;
        float4 o;
        o.x = acc[i][0]; o.y = acc[i][1]; o.z = acc[i][2]; o.w = acc[i][3];
        *(float4*)(pt + ((size_t)kt * 256 + row) * DIM + nb + (tx << 2)) = o;
    }
    if (nb == 0) {
        // 8 threads sharing row m partition its 128-s chunk; shuffle-sum them.
#pragma unroll
        for (int r = 0; r < 2; ++r) {
            float v = rsum[r];
            v += __shfl_xor(v, 1, 64);
            v += __shfl_xor(v, 2, 64);
            v += __shfl_xor(v, 4, 64);
            if ((t & 7) == 0) {
                int m = (t >> 3) + r * 32;
                sums_p[kt * 256 + b * 64 + m] = v;
            }
        }
    }
}

// out = (sum_{kt} pt[kt]) / (sum_{kt} sums_p[kt]). 32768 float4s.
__global__ __launch_bounds__(256) void reduce_kernel(
    const float* __restrict__ pt, const float* __restrict__ sums_p,
    float* __restrict__ out)
{
    int idx = blockIdx.x * 256 + threadIdx.x;
    const float4* p = (const float4*)pt;
    float4 a = p[idx];
#pragma unroll
    for (int k = 1; k < 8; ++k) {
        float4 v = p[k * 32768 + idx];
        a.x += v.x; a.y += v.y; a.z += v.z; a.w += v.w;
    }
    int row = idx >> 7;
    float s = 0.f;
#pragma unroll
    for (int k = 0; k < 8; ++k) s += sums_p[k * 256 + row];
    float r = fast_rcp(s);
    a.x *= r; a.y *= r; a.z *= r; a.w *= r;
    ((float4*)out)[idx] = a;
}

extern "C" void kernel_launch(void* const* d_in, const int* in_sizes, int n_in,
                              void* d_out, int out_size, void* d_ws, size_t ws_size,
                              hipStream_t stream) {
    const float* queries = (const float*)d_in[0];
    const float* keys    = (const float*)d_in[1];
    const float* values  = (const float*)d_in[2];
    const float* W1      = (const float*)d_in[3];
    const float* b1      = (const float*)d_in[4];
    const float* w2      = (const float*)d_in[5];
    float* out = (float*)d_out;

    float* qp     = (float*)d_ws;                   // 131072 f32 (Eq)
    float* kp     = qp + 131072;                    // 2097152 f32 (Ek)
    float* th     = kp + 2097152;                   // 2 x 262144 f32
    float* pt     = th + 2 * 262144;                // 8 x 131072 f32
    float* sums_p = pt + 8 * 131072;                // 2048 f32
    unsigned short* qbf = (unsigned short*)(sums_p + 2048);
    unsigned short* kbf = qbf + 131072;
    unsigned short* wbf = kbf + 2097152;
    (void)in_sizes; (void)n_in; (void)ws_size; (void)out_size;

    convert_bf16<<<dim3(2688), 256, 0, stream>>>(queries, keys, W1, qbf, kbf, wbf);
    proj_mfma<<<dim3(544), 256, 0, stream>>>(qbf, kbf, wbf, b1, qp, kp);
    scores_kernel<<<dim3(32, 8, 4), 256, 0, stream>>>(qp, kp, w2, th);
    av_gemm<<<dim3(8, 8, 4), 256, 0, stream>>>(th, values, pt, sums_p);
    reduce_kernel<<<dim3(128), 256, 0, stream>>>(pt, sums_p, out);
}